// Round 10
// baseline (901.488 us; speedup 1.0000x reference)
//
#include <hip/hip_runtime.h>
#include <hip/hip_bf16.h>

typedef short bf16x8 __attribute__((ext_vector_type(8)));
typedef float f32x16 __attribute__((ext_vector_type(16)));

#define NB 8
#define NPTS 8192
#define NSET (NB * NPTS)
#define CHUNK_BYTES 16384   // 16 col-tiles of 1KB
#define NCHUNK 4            // 64 tiles = 2048 cols per block
#define NCOLQ 4
#define NROWG 32

static __device__ __forceinline__ short bfbits(float x) {
    __hip_bfloat16 h = __float2bfloat16(x);  // RNE
    return *reinterpret_cast<short*>(&h);
}
static __device__ __forceinline__ float bfval(float x) {
    __hip_bfloat16 h = __float2bfloat16(x);
    return __bfloat162float(h);
}

// target points -> A row-features (linear); pred points -> B col-features
// (FRAGMENT ORDER per 32-pt tile: tile*1024B, khalf-major). dot(A_t,B_p) =
// |t|^2+|p|^2-2t.p via hi/lo bf16 split. Only ONE direction is needed now.
__global__ __launch_bounds__(256) void pack2_kernel(
    const float* __restrict__ target, const float* __restrict__ pred,
    short* __restrict__ tA, short* __restrict__ pB) {
    int gi = blockIdx.x * 256 + threadIdx.x;
    int second = gi >= NSET;                  // pred set
    int i = second ? gi - NSET : gi;
    const float* pts = second ? pred : target;

    float x = pts[3 * i + 0], y = pts[3 * i + 1], z = pts[3 * i + 2];
    float n2 = x * x + y * y + z * z;

    float xh = bfval(x), yh = bfval(y), zh = bfval(z), nh = bfval(n2);
    short xhb = bfbits(x), yhb = bfbits(y), zhb = bfbits(z), nhb = bfbits(n2);
    short xlb = bfbits(x - xh), ylb = bfbits(y - yh), zlb = bfbits(z - zh), nlb = bfbits(n2 - nh);
    short one = bfbits(1.0f);

    if (!second) {
        // A k=0..15: [1,1,n2h,n2l, xh,xh,xl, yh,yh,yl, zh,zh,zl, 0,0,0]
        bf16x8 a0, a1;
        a0[0] = one; a0[1] = one; a0[2] = nhb; a0[3] = nlb;
        a0[4] = xhb; a0[5] = xhb; a0[6] = xlb; a0[7] = yhb;
        a1[0] = yhb; a1[1] = ylb; a1[2] = zhb; a1[3] = zhb;
        a1[4] = zlb; a1[5] = 0;   a1[6] = 0;   a1[7] = 0;
        *reinterpret_cast<bf16x8*>(&tA[(size_t)i * 16])     = a0;
        *reinterpret_cast<bf16x8*>(&tA[(size_t)i * 16 + 8]) = a1;
    } else {
        short mxh = bfbits(-2.0f * xh), myh = bfbits(-2.0f * yh), mzh = bfbits(-2.0f * zh);
        short mxl = bfbits(-2.0f * __bfloat162float(*(__hip_bfloat16*)&xlb));
        short myl = bfbits(-2.0f * __bfloat162float(*(__hip_bfloat16*)&ylb));
        short mzl = bfbits(-2.0f * __bfloat162float(*(__hip_bfloat16*)&zlb));
        // B k=0..15: [n2h,n2l,1,1, -2xh,-2xl,-2xh, -2yh,-2yl,-2yh, -2zh,-2zl,-2zh, 0,0,0]
        bf16x8 b0, b1;
        b0[0] = nhb; b0[1] = nlb; b0[2] = one; b0[3] = one;
        b0[4] = mxh; b0[5] = mxl; b0[6] = mxh; b0[7] = myh;
        b1[0] = myl; b1[1] = myh; b1[2] = mzh; b1[3] = mzl;
        b1[4] = mzh; b1[5] = 0;   b1[6] = 0;   b1[7] = 0;
        int bb = i >> 13;
        int pi = i & (NPTS - 1);
        int tile = pi >> 5, l = pi & 31;
        short* Bp = pB + (size_t)bb * NPTS * 16 + tile * 512;
        *reinterpret_cast<bf16x8*>(Bp + l * 8)       = b0;   // khalf 0
        *reinterpret_cast<bf16x8*>(Bp + 256 + l * 8) = b1;   // khalf 1
    }
}

// Stage one 16KB chunk (16 tiles) global->LDS; each wave copies 4x1KB.
static __device__ __forceinline__ void stage_chunk(char* ldsbase, const char* gsrc,
                                                   int wave, int lane) {
#pragma unroll
    for (int s = 0; s < 4; ++s) {
        int off = s * 4096 + wave * 1024;
        __builtin_amdgcn_global_load_lds(
            (const __attribute__((address_space(1))) unsigned int*)(gsrc + off + lane * 16),
            (__attribute__((address_space(3))) unsigned int*)(ldsbase + off),
            16, 0, 0);
    }
}

// lane-merge: combine two row-registers across lane-pairs (xor m).
#define MERGE(dst, u, v, m) {                       \
    float _own = (lane & (m)) ? (v) : (u);          \
    float _sel = (lane & (m)) ? (u) : (v);          \
    dst = fminf(_own, __shfl_xor(_sel, (m))); }

// sequential chain -> v_min3_f32 pairs
static __device__ __forceinline__ float fold16(float m, const f32x16& v) {
#pragma unroll
    for (int r = 0; r < 16; ++r) m = fminf(m, v[r]);
    return m;
}

// ONE fused pass: rows = 256 target pts, cols = 2048 pred pts per block.
// Grid 1024 = 8 b x 32 rowgrp x 4 colq; 4 blocks/CU (40KB LDS each).
// Row-mins: register min3-fold -> log-merge -> store partial per colq.
// Col-mins: per-tile fold chain -> h-merge -> LDS atomicMin -> one flush
// per block to colminpart[b][colq][rowgrp][2048]. No global atomics, no init.
__global__ __launch_bounds__(256, 4) void chamfer_fused_kernel(
    const short* __restrict__ targA, const short* __restrict__ predB,
    float* __restrict__ rowminpart,   // [NCOLQ][NSET]
    float* __restrict__ colminpart)   // [NB][NCOLQ][NROWG][2048]
{
    __shared__ __align__(16) char smem[2][CHUNK_BYTES];
    __shared__ int colmin_lds[2048];

    const int bid  = blockIdx.x;
    const int b    = bid >> 7;
    const int rowgrp = (bid >> 2) & 31;
    const int colq   = bid & 3;
    const int wave = threadIdx.x >> 6;
    const int lane = threadIdx.x & 63;
    const int l31  = lane & 31, h = lane >> 5;

    // init block-local colmin to +huge (covered by first loop barrier)
    for (int idx = threadIdx.x; idx < 2048; idx += 256)
        colmin_lds[idx] = 0x7F7F7F7F;

    const int row0 = rowgrp * 256 + wave * 64;
    const short* abase = targA + ((size_t)(b * NPTS + row0 + l31)) * 16 + h * 8;
    bf16x8 a0 = *reinterpret_cast<const bf16x8*>(abase);            // rows +0..31
    bf16x8 a1 = *reinterpret_cast<const bf16x8*>(abase + 32 * 16);  // rows +32..63

    const char* bsrc = (const char*)predB + (size_t)b * NPTS * 32
                     + (size_t)colq * 2048 * 32;   // 64KB frag-ordered quarter

    float acc0[16], acc1[16];
#pragma unroll
    for (int r = 0; r < 16; ++r) { acc0[r] = 3.4e38f; acc1[r] = 3.4e38f; }

    const f32x16 z = {0.f,0.f,0.f,0.f, 0.f,0.f,0.f,0.f, 0.f,0.f,0.f,0.f, 0.f,0.f,0.f,0.f};

    stage_chunk(smem[0], bsrc, wave, lane);

    for (int c = 0; c < NCHUNK; ++c) {
        __syncthreads();   // chunk c staged (vmcnt drained at barrier)
        if (c + 1 < NCHUNK)
            stage_chunk(smem[(c + 1) & 1], bsrc + (size_t)(c + 1) * CHUNK_BYTES, wave, lane);
        const char* bufc = smem[c & 1];
#pragma unroll
        for (int t = 0; t < 16; t += 2) {
            bf16x8 bA = *reinterpret_cast<const bf16x8*>(bufc + t * 1024 + lane * 16);
            bf16x8 bB = *reinterpret_cast<const bf16x8*>(bufc + t * 1024 + 1024 + lane * 16);
            f32x16 ca = __builtin_amdgcn_mfma_f32_32x32x16_bf16(a0, bA, z, 0, 0, 0);
            f32x16 cb = __builtin_amdgcn_mfma_f32_32x32x16_bf16(a0, bB, z, 0, 0, 0);
            f32x16 da = __builtin_amdgcn_mfma_f32_32x32x16_bf16(a1, bA, z, 0, 0, 0);
            f32x16 db = __builtin_amdgcn_mfma_f32_32x32x16_bf16(a1, bB, z, 0, 0, 0);
            // row-min fold (min3)
#pragma unroll
            for (int r = 0; r < 16; ++r)
                acc0[r] = fminf(fminf(acc0[r], ca[r]), cb[r]);
#pragma unroll
            for (int r = 0; r < 16; ++r)
                acc1[r] = fminf(fminf(acc1[r], da[r]), db[r]);
            // col-min fold: tile A cols (bA) over 64 rows, tile B cols (bB)
            float cmA = fold16(fold16(3.4e38f, ca), da);
            cmA = fminf(cmA, __shfl_xor(cmA, 32));
            float cmB = fold16(fold16(3.4e38f, cb), db);
            cmB = fminf(cmB, __shfl_xor(cmB, 32));
            int cbase = (c * 16 + t) * 32;
            if (h == 0) {
                atomicMin(&colmin_lds[cbase + l31],      __float_as_int(fmaxf(cmA, 0.0f)));
                atomicMin(&colmin_lds[cbase + 32 + l31], __float_as_int(fmaxf(cmB, 0.0f)));
            }
        }
    }

    // log-merge: 32 regs x 32-lane col-min -> each lane holds one row's min
    // over this col-quarter.
#pragma unroll
    for (int k = 0; k < 8; ++k) { MERGE(acc0[k], acc0[2*k], acc0[2*k+1], 1); }
#pragma unroll
    for (int k = 0; k < 8; ++k) { MERGE(acc1[k], acc1[2*k], acc1[2*k+1], 1); }
#pragma unroll
    for (int k = 0; k < 4; ++k) { MERGE(acc0[k], acc0[2*k], acc0[2*k+1], 2); }
#pragma unroll
    for (int k = 0; k < 4; ++k) { MERGE(acc1[k], acc1[2*k], acc1[2*k+1], 2); }
#pragma unroll
    for (int k = 0; k < 2; ++k) { MERGE(acc0[k], acc0[2*k], acc0[2*k+1], 4); }
#pragma unroll
    for (int k = 0; k < 2; ++k) { MERGE(acc1[k], acc1[2*k], acc1[2*k+1], 4); }
    MERGE(acc0[0], acc0[0], acc0[1], 8);
    MERGE(acc1[0], acc1[0], acc1[1], 8);
    float fin;
    MERGE(fin, acc0[0], acc1[0], 16);
    // row(lane) map verified r7-r9
    int row = (lane & 3) + 4 * ((lane >> 5) & 1) + 8 * ((lane >> 2) & 1)
            + 16 * ((lane >> 3) & 1) + 32 * ((lane >> 4) & 1);
    rowminpart[(size_t)colq * NSET + b * NPTS + row0 + row] = fin;

    // flush block-local colmin partials (one coalesced store sweep)
    __syncthreads();
    float* cdst = colminpart + (((size_t)b * NCOLQ + colq) * NROWG + rowgrp) * 2048;
    for (int idx = threadIdx.x; idx < 2048; idx += 256)
        cdst[idx] = __int_as_float(colmin_lds[idx]);
}

// Combine partials: dist1 row i = min over 4 colq; dist2 col j = min over 32
// rowgroups. Grid-stride sum -> one partial per block (no atomics).
__global__ __launch_bounds__(256) void reduce_kernel(
    const float* __restrict__ rowminpart, const float* __restrict__ colminpart,
    float* __restrict__ partials) {
    const int stride = gridDim.x * 256;
    float v = 0.0f;
    for (int i = blockIdx.x * 256 + threadIdx.x; i < 2 * NSET; i += stride) {
        if (i < NSET) {
            float m =       rowminpart[i];
            m = fminf(m,    rowminpart[NSET + i]);
            m = fminf(m,    rowminpart[2 * (size_t)NSET + i]);
            m = fminf(m,    rowminpart[3 * (size_t)NSET + i]);
            v += m;
        } else {
            int j = i - NSET;
            int bb = j >> 13, col = j & (NPTS - 1);
            int cq = col >> 11, cc = col & 2047;
            const float* p = colminpart + (((size_t)bb * NCOLQ + cq) * NROWG) * 2048 + cc;
            float m = p[0];
#pragma unroll
            for (int g = 1; g < NROWG; ++g) m = fminf(m, p[(size_t)g * 2048]);
            v += m;
        }
    }
#pragma unroll
    for (int o = 32; o > 0; o >>= 1) v += __shfl_xor(v, o);
    __shared__ float wpart[4];
    if ((threadIdx.x & 63) == 0) wpart[threadIdx.x >> 6] = v;
    __syncthreads();
    if (threadIdx.x == 0)
        partials[blockIdx.x] = wpart[0] + wpart[1] + wpart[2] + wpart[3];
}

// Single block: sum 256 partials, scale, store.
__global__ __launch_bounds__(256) void final_kernel(const float* __restrict__ partials,
                                                    float* __restrict__ out) {
    __shared__ float wpart[4];
    float v = partials[threadIdx.x];
#pragma unroll
    for (int o = 32; o > 0; o >>= 1) v += __shfl_xor(v, o);
    if ((threadIdx.x & 63) == 0) wpart[threadIdx.x >> 6] = v;
    __syncthreads();
    if (threadIdx.x == 0)
        out[0] = (wpart[0] + wpart[1] + wpart[2] + wpart[3]) * (1.0f / (float)NSET);
}

extern "C" void kernel_launch(void* const* d_in, const int* in_sizes, int n_in,
                              void* d_out, int out_size, void* d_ws, size_t ws_size,
                              hipStream_t stream) {
    const float* pred   = (const float*)d_in[0];   // [8,8192,3]
    const float* target = (const float*)d_in[1];   // [8,8192,3]
    float* out = (float*)d_out;

    char* ws = (char*)d_ws;
    float* rowminpart = (float*)ws;                                  // 4*NSET = 1MB
    float* colminpart = rowminpart + (size_t)NCOLQ * NSET;           // 8*4*32*2048 = 8MB
    float* partials   = colminpart + (size_t)NB * NCOLQ * NROWG * 2048;  // 256 floats
    short* tA = (short*)(ws + 16 * 1024 * 1024);                     // 2 MB
    short* pB = tA + (size_t)NSET * 16;                              // 2 MB

    pack2_kernel<<<2 * NSET / 256, 256, 0, stream>>>(target, pred, tA, pB);

    chamfer_fused_kernel<<<1024, 256, 0, stream>>>(tA, pB, rowminpart, colminpart);

    reduce_kernel<<<256, 256, 0, stream>>>(rowminpart, colminpart, partials);
    final_kernel<<<1, 256, 0, stream>>>(partials, out);
}

// Round 11
// 64.770 us; speedup vs baseline: 13.9183x; 13.9183x over previous
//
#include <hip/hip_runtime.h>
#include <hip/hip_bf16.h>

typedef short bf16x8 __attribute__((ext_vector_type(8)));
typedef float f32x16 __attribute__((ext_vector_type(16)));

#define NB 8
#define NPTS 8192
#define NSET (NB * NPTS)
#define CHUNK_BYTES 16384   // 16 col-tiles of 1KB
#define NCHUNK 8            // 128 tiles per col-half

static __device__ __forceinline__ short bfbits(float x) {
    __hip_bfloat16 h = __float2bfloat16(x);  // RNE
    return *reinterpret_cast<short*>(&h);
}
static __device__ __forceinline__ float bfval(float x) {
    __hip_bfloat16 h = __float2bfloat16(x);
    return __bfloat162float(h);
}

// Per point, emit K=16 bf16 row-features (A, linear) and col-features (B,
// FRAGMENT ORDER per 32-pt tile: tile*1024B, khalf-major) so that
// dot(A_t, B_p) = |t|^2 + |p|^2 - 2 t.p  (hi/lo bf16 split).
__global__ __launch_bounds__(256) void pack2_kernel(
    const float* __restrict__ target, const float* __restrict__ pred,
    short* __restrict__ tA, short* __restrict__ tB,
    short* __restrict__ pA, short* __restrict__ pB) {
    int gi = blockIdx.x * 256 + threadIdx.x;
    int second = gi >= NSET;
    int i = second ? gi - NSET : gi;
    const float* pts = second ? pred : target;
    short* A = second ? pA : tA;
    short* B = second ? pB : tB;

    float x = pts[3 * i + 0], y = pts[3 * i + 1], z = pts[3 * i + 2];
    float n2 = x * x + y * y + z * z;

    float xh = bfval(x), yh = bfval(y), zh = bfval(z), nh = bfval(n2);
    short xhb = bfbits(x), yhb = bfbits(y), zhb = bfbits(z), nhb = bfbits(n2);
    short xlb = bfbits(x - xh), ylb = bfbits(y - yh), zlb = bfbits(z - zh), nlb = bfbits(n2 - nh);
    short one = bfbits(1.0f);
    short mxh = bfbits(-2.0f * xh), myh = bfbits(-2.0f * yh), mzh = bfbits(-2.0f * zh);
    short mxl = bfbits(-2.0f * __bfloat162float(*(__hip_bfloat16*)&xlb));
    short myl = bfbits(-2.0f * __bfloat162float(*(__hip_bfloat16*)&ylb));
    short mzl = bfbits(-2.0f * __bfloat162float(*(__hip_bfloat16*)&zlb));

    // A k=0..15: [1,1,n2h,n2l, xh,xh,xl, yh,yh,yl, zh,zh,zl, 0,0,0]
    bf16x8 a0, a1, b0, b1;
    a0[0] = one; a0[1] = one; a0[2] = nhb; a0[3] = nlb;
    a0[4] = xhb; a0[5] = xhb; a0[6] = xlb; a0[7] = yhb;
    a1[0] = yhb; a1[1] = ylb; a1[2] = zhb; a1[3] = zhb;
    a1[4] = zlb; a1[5] = 0;   a1[6] = 0;   a1[7] = 0;
    // B k=0..15: [n2h,n2l,1,1, -2xh,-2xl,-2xh, -2yh,-2yl,-2yh, -2zh,-2zl,-2zh, 0,0,0]
    b0[0] = nhb; b0[1] = nlb; b0[2] = one; b0[3] = one;
    b0[4] = mxh; b0[5] = mxl; b0[6] = mxh; b0[7] = myh;
    b1[0] = myl; b1[1] = myh; b1[2] = mzh; b1[3] = mzl;
    b1[4] = mzh; b1[5] = 0;   b1[6] = 0;   b1[7] = 0;

    *reinterpret_cast<bf16x8*>(&A[(size_t)i * 16])     = a0;
    *reinterpret_cast<bf16x8*>(&A[(size_t)i * 16 + 8]) = a1;

    int bb = i >> 13;                 // batch
    int pi = i & (NPTS - 1);
    int tile = pi >> 5, l = pi & 31;
    short* Bp = B + (size_t)bb * NPTS * 16 + tile * 512;
    *reinterpret_cast<bf16x8*>(Bp + l * 8)       = b0;   // khalf 0
    *reinterpret_cast<bf16x8*>(Bp + 256 + l * 8) = b1;   // khalf 1
}

// Stage one 16KB chunk (16 tiles) global->LDS; each wave copies 4x1KB.
static __device__ __forceinline__ void stage_chunk(char* ldsbase, const char* gsrc,
                                                   int wave, int lane) {
#pragma unroll
    for (int s = 0; s < 4; ++s) {
        int off = s * 4096 + wave * 1024;
        __builtin_amdgcn_global_load_lds(
            (const __attribute__((address_space(1))) unsigned int*)(gsrc + off + lane * 16),
            (__attribute__((address_space(3))) unsigned int*)(ldsbase + off),
            16, 0, 0);
    }
}

// lane-merge: combine two row-registers across lane-pairs (xor m).
#define MERGE(dst, u, v, m) {                       \
    float _own = (lane & (m)) ? (v) : (u);          \
    float _sel = (lane & (m)) ? (u) : (v);          \
    dst = fminf(_own, __shfl_xor(_sel, (m))); }

// shared epilogue: 32 regs x 32-lane col-min -> lane-per-row -> rowmin store
#define EPILOGUE()                                                             \
    _Pragma("unroll") for (int k = 0; k < 8; ++k) { MERGE(acc0[k], acc0[2*k], acc0[2*k+1], 1); } \
    _Pragma("unroll") for (int k = 0; k < 8; ++k) { MERGE(acc1[k], acc1[2*k], acc1[2*k+1], 1); } \
    _Pragma("unroll") for (int k = 0; k < 4; ++k) { MERGE(acc0[k], acc0[2*k], acc0[2*k+1], 2); } \
    _Pragma("unroll") for (int k = 0; k < 4; ++k) { MERGE(acc1[k], acc1[2*k], acc1[2*k+1], 2); } \
    _Pragma("unroll") for (int k = 0; k < 2; ++k) { MERGE(acc0[k], acc0[2*k], acc0[2*k+1], 4); } \
    _Pragma("unroll") for (int k = 0; k < 2; ++k) { MERGE(acc1[k], acc1[2*k], acc1[2*k+1], 4); } \
    MERGE(acc0[0], acc0[0], acc0[1], 8);                                       \
    MERGE(acc1[0], acc1[0], acc1[1], 8);                                       \
    float fin;                                                                 \
    MERGE(fin, acc0[0], acc1[0], 16);                                          \
    int row = (lane & 3) + 4 * ((lane >> 5) & 1) + 8 * ((lane >> 2) & 1)       \
            + 16 * ((lane >> 3) & 1) + 32 * ((lane >> 4) & 1);                 \
    rowmin[((size_t)(pass * 2 + colhalf)) * NSET + b * NPTS + row0 + row] = fin;

// V1: batches 0-3. 3-buffer LDS pipeline, raw s_barrier + counted vmcnt
// (never 0 mid-loop) -- next-chunk loads stay in flight across the barrier.
__global__ __launch_bounds__(256, 4) void chamfer_v1_kernel(
    const short* __restrict__ targA, const short* __restrict__ targB,
    const short* __restrict__ predA, const short* __restrict__ predB,
    float* __restrict__ rowmin)   // [2 dir][2 half][NSET]
{
    __shared__ __align__(16) char smem[3][CHUNK_BYTES];

    const int bid  = blockIdx.x;
    const int pass = bid >> 8;
    const int b    = (bid >> 6) & 3;       // batches 0..3
    const int rowgrp  = (bid >> 1) & 31;
    const int colhalf = bid & 1;
    const int wave = threadIdx.x >> 6;
    const int lane = threadIdx.x & 63;
    const int l31  = lane & 31, h = lane >> 5;

    const short* Af = pass ? predA : targA;
    const short* Bf = pass ? targB : predB;

    const int row0 = rowgrp * 256 + wave * 64;
    const short* abase = Af + ((size_t)(b * NPTS + row0 + l31)) * 16 + h * 8;
    bf16x8 a0 = *reinterpret_cast<const bf16x8*>(abase);
    bf16x8 a1 = *reinterpret_cast<const bf16x8*>(abase + 32 * 16);

    const char* bsrc = (const char*)Bf + (size_t)b * NPTS * 32
                     + (size_t)colhalf * (NPTS / 2) * 32;

    float acc0[16], acc1[16];
#pragma unroll
    for (int r = 0; r < 16; ++r) { acc0[r] = 3.4e38f; acc1[r] = 3.4e38f; }

    const f32x16 z = {0.f,0.f,0.f,0.f, 0.f,0.f,0.f,0.f, 0.f,0.f,0.f,0.f, 0.f,0.f,0.f,0.f};

    stage_chunk(smem[0], bsrc, wave, lane);
    stage_chunk(smem[1], bsrc + CHUNK_BYTES, wave, lane);

    for (int c = 0; c < NCHUNK; ++c) {
        // wait chunk c's 4 loads (the c+1 chunk's 4 stay in flight)
        if (c + 1 < NCHUNK) asm volatile("s_waitcnt vmcnt(4)" ::: "memory");
        else                asm volatile("s_waitcnt vmcnt(0)" ::: "memory");
        __builtin_amdgcn_s_barrier();   // all waves: c landed, c-1 fully computed
        __builtin_amdgcn_sched_barrier(0);
        if (c + 2 < NCHUNK)
            stage_chunk(smem[(c + 2) % 3], bsrc + (size_t)(c + 2) * CHUNK_BYTES, wave, lane);
        const char* bufc = smem[c % 3];
#pragma unroll
        for (int t = 0; t < 16; t += 2) {
            bf16x8 bA = *reinterpret_cast<const bf16x8*>(bufc + t * 1024 + lane * 16);
            bf16x8 bB = *reinterpret_cast<const bf16x8*>(bufc + t * 1024 + 1024 + lane * 16);
            f32x16 ca = __builtin_amdgcn_mfma_f32_32x32x16_bf16(a0, bA, z, 0, 0, 0);
            f32x16 cb = __builtin_amdgcn_mfma_f32_32x32x16_bf16(a0, bB, z, 0, 0, 0);
#pragma unroll
            for (int r = 0; r < 16; ++r)
                acc0[r] = fminf(fminf(acc0[r], ca[r]), cb[r]);  // -> v_min3_f32
            f32x16 da = __builtin_amdgcn_mfma_f32_32x32x16_bf16(a1, bA, z, 0, 0, 0);
            f32x16 db = __builtin_amdgcn_mfma_f32_32x32x16_bf16(a1, bB, z, 0, 0, 0);
#pragma unroll
            for (int r = 0; r < 16; ++r)
                acc1[r] = fminf(fminf(acc1[r], da[r]), db[r]);
        }
    }

    EPILOGUE();
}

// V2: batches 4-7. No LDS: direct-global frag-ordered loads, depth-2
// register prefetch (issue ~2 pair-iters ahead of use > L2 latency).
__global__ __launch_bounds__(256, 2) void chamfer_v2_kernel(
    const short* __restrict__ targA, const short* __restrict__ targB,
    const short* __restrict__ predA, const short* __restrict__ predB,
    float* __restrict__ rowmin)
{
    const int bid  = blockIdx.x;
    const int pass = bid >> 8;
    const int b    = 4 + ((bid >> 6) & 3);   // batches 4..7
    const int rowgrp  = (bid >> 1) & 31;
    const int colhalf = bid & 1;
    const int wave = threadIdx.x >> 6;
    const int lane = threadIdx.x & 63;
    const int l31  = lane & 31, h = lane >> 5;
    (void)wave;

    const short* Af = pass ? predA : targA;
    const short* Bf = pass ? targB : predB;

    const int row0 = rowgrp * 256 + wave * 64;
    const short* abase = Af + ((size_t)(b * NPTS + row0 + l31)) * 16 + h * 8;
    bf16x8 a0 = *reinterpret_cast<const bf16x8*>(abase);
    bf16x8 a1 = *reinterpret_cast<const bf16x8*>(abase + 32 * 16);

    const char* bbase = (const char*)Bf + (size_t)b * NPTS * 32
                      + (size_t)colhalf * (NPTS / 2) * 32;

    float acc0[16], acc1[16];
#pragma unroll
    for (int r = 0; r < 16; ++r) { acc0[r] = 3.4e38f; acc1[r] = 3.4e38f; }

    const f32x16 z = {0.f,0.f,0.f,0.f, 0.f,0.f,0.f,0.f, 0.f,0.f,0.f,0.f, 0.f,0.f,0.f,0.f};

#define LDT(t) (*reinterpret_cast<const bf16x8*>(bbase + (size_t)(t) * 1024 + lane * 16))
    bf16x8 c0a = LDT(0), c0b = LDT(1);
    bf16x8 c1a = LDT(2), c1b = LDT(3);

    for (int it = 0; it < 64; ++it) {
        bf16x8 n0, n1;
        if (it < 62) { n0 = LDT(2 * it + 4); n1 = LDT(2 * it + 5); }
        f32x16 ca = __builtin_amdgcn_mfma_f32_32x32x16_bf16(a0, c0a, z, 0, 0, 0);
        f32x16 cb = __builtin_amdgcn_mfma_f32_32x32x16_bf16(a0, c0b, z, 0, 0, 0);
#pragma unroll
        for (int r = 0; r < 16; ++r)
            acc0[r] = fminf(fminf(acc0[r], ca[r]), cb[r]);
        f32x16 da = __builtin_amdgcn_mfma_f32_32x32x16_bf16(a1, c0a, z, 0, 0, 0);
        f32x16 db = __builtin_amdgcn_mfma_f32_32x32x16_bf16(a1, c0b, z, 0, 0, 0);
#pragma unroll
        for (int r = 0; r < 16; ++r)
            acc1[r] = fminf(fminf(acc1[r], da[r]), db[r]);
        c0a = c1a; c0b = c1b; c1a = n0; c1b = n1;
    }
#undef LDT

    EPILOGUE();
}

// min the two col-halves, sum -> one partial per block (no atomics).
__global__ __launch_bounds__(256) void reduce_kernel(const float* __restrict__ rowmin,
                                                     float* __restrict__ partials) {
    const int stride = gridDim.x * 256;
    float v = 0.0f;
    for (int i = blockIdx.x * 256 + threadIdx.x; i < 2 * NSET; i += stride) {
        int d = i >> 16;   // NSET = 65536
        size_t base = (size_t)i + (size_t)d * NSET;
        v += fminf(rowmin[base], rowmin[base + NSET]);
    }
#pragma unroll
    for (int o = 32; o > 0; o >>= 1) v += __shfl_xor(v, o);
    __shared__ float wpart[4];
    if ((threadIdx.x & 63) == 0) wpart[threadIdx.x >> 6] = v;
    __syncthreads();
    if (threadIdx.x == 0)
        partials[blockIdx.x] = wpart[0] + wpart[1] + wpart[2] + wpart[3];
}

__global__ __launch_bounds__(128) void final_kernel(const float* __restrict__ partials,
                                                    float* __restrict__ out) {
    __shared__ float wpart[2];
    float v = partials[threadIdx.x];
#pragma unroll
    for (int o = 32; o > 0; o >>= 1) v += __shfl_xor(v, o);
    if ((threadIdx.x & 63) == 0) wpart[threadIdx.x >> 6] = v;
    __syncthreads();
    if (threadIdx.x == 0)
        out[0] = (wpart[0] + wpart[1]) * (1.0f / (float)NSET);
}

extern "C" void kernel_launch(void* const* d_in, const int* in_sizes, int n_in,
                              void* d_out, int out_size, void* d_ws, size_t ws_size,
                              hipStream_t stream) {
    const float* pred   = (const float*)d_in[0];   // [8,8192,3]
    const float* target = (const float*)d_in[1];   // [8,8192,3]
    float* out = (float*)d_out;

    char* ws = (char*)d_ws;
    float* rowmin   = (float*)ws;                       // 4*NSET floats = 1MB
    float* partials = rowmin + (size_t)4 * NSET;        // 128 floats
    short* tA = (short*)(ws + (size_t)4 * NSET * 4 + 4096);  // each 2 MB
    short* tB = tA + (size_t)NSET * 16;
    short* pA = tB + (size_t)NSET * 16;
    short* pB = pA + (size_t)NSET * 16;

    pack2_kernel<<<2 * NSET / 256, 256, 0, stream>>>(target, pred, tA, tB, pA, pB);

    // A/B at equal half-work: V1 = counted-vmcnt LDS pipeline (batches 0-3),
    // V2 = direct-global depth-2 prefetch (batches 4-7).
    chamfer_v1_kernel<<<512, 256, 0, stream>>>(tA, tB, pA, pB, rowmin);
    chamfer_v2_kernel<<<512, 256, 0, stream>>>(tA, tB, pA, pB, rowmin);

    reduce_kernel<<<128, 256, 0, stream>>>(rowmin, partials);
    final_kernel<<<1, 128, 0, stream>>>(partials, out);
}

// Round 12
// 55.582 us; speedup vs baseline: 16.2190x; 1.1653x over previous
//
#include <hip/hip_runtime.h>
#include <hip/hip_bf16.h>

typedef short bf16x8 __attribute__((ext_vector_type(8)));
typedef float f32x16 __attribute__((ext_vector_type(16)));

#define NB 8
#define NPTS 8192
#define NSET (NB * NPTS)

static __device__ __forceinline__ short bfbits(float x) {
    __hip_bfloat16 h = __float2bfloat16(x);  // RNE
    return *reinterpret_cast<short*>(&h);
}
static __device__ __forceinline__ float bfval(float x) {
    __hip_bfloat16 h = __float2bfloat16(x);
    return __bfloat162float(h);
}

// Per point, emit K=16 bf16 row-features (A, linear) and col-features (B,
// FRAGMENT ORDER per 32-pt tile: tile*1024B; lane reads its frag at
// tile*1024 + lane*16) so that dot(A_t, B_p) = |t|^2+|p|^2-2t.p (hi/lo split).
__global__ __launch_bounds__(256) void pack2_kernel(
    const float* __restrict__ target, const float* __restrict__ pred,
    short* __restrict__ tA, short* __restrict__ tB,
    short* __restrict__ pA, short* __restrict__ pB) {
    int gi = blockIdx.x * 256 + threadIdx.x;
    int second = gi >= NSET;
    int i = second ? gi - NSET : gi;
    const float* pts = second ? pred : target;
    short* A = second ? pA : tA;
    short* B = second ? pB : tB;

    float x = pts[3 * i + 0], y = pts[3 * i + 1], z = pts[3 * i + 2];
    float n2 = x * x + y * y + z * z;

    float xh = bfval(x), yh = bfval(y), zh = bfval(z), nh = bfval(n2);
    short xhb = bfbits(x), yhb = bfbits(y), zhb = bfbits(z), nhb = bfbits(n2);
    short xlb = bfbits(x - xh), ylb = bfbits(y - yh), zlb = bfbits(z - zh), nlb = bfbits(n2 - nh);
    short one = bfbits(1.0f);
    short mxh = bfbits(-2.0f * xh), myh = bfbits(-2.0f * yh), mzh = bfbits(-2.0f * zh);
    short mxl = bfbits(-2.0f * __bfloat162float(*(__hip_bfloat16*)&xlb));
    short myl = bfbits(-2.0f * __bfloat162float(*(__hip_bfloat16*)&ylb));
    short mzl = bfbits(-2.0f * __bfloat162float(*(__hip_bfloat16*)&zlb));

    // A k=0..15: [1,1,n2h,n2l, xh,xh,xl, yh,yh,yl, zh,zh,zl, 0,0,0]
    bf16x8 a0, a1, b0, b1;
    a0[0] = one; a0[1] = one; a0[2] = nhb; a0[3] = nlb;
    a0[4] = xhb; a0[5] = xhb; a0[6] = xlb; a0[7] = yhb;
    a1[0] = yhb; a1[1] = ylb; a1[2] = zhb; a1[3] = zhb;
    a1[4] = zlb; a1[5] = 0;   a1[6] = 0;   a1[7] = 0;
    // B k=0..15: [n2h,n2l,1,1, -2xh,-2xl,-2xh, -2yh,-2yl,-2yh, -2zh,-2zl,-2zh, 0,0,0]
    b0[0] = nhb; b0[1] = nlb; b0[2] = one; b0[3] = one;
    b0[4] = mxh; b0[5] = mxl; b0[6] = mxh; b0[7] = myh;
    b1[0] = myl; b1[1] = myh; b1[2] = mzh; b1[3] = mzl;
    b1[4] = mzh; b1[5] = 0;   b1[6] = 0;   b1[7] = 0;

    *reinterpret_cast<bf16x8*>(&A[(size_t)i * 16])     = a0;
    *reinterpret_cast<bf16x8*>(&A[(size_t)i * 16 + 8]) = a1;

    int bb = i >> 13;                 // batch
    int pi = i & (NPTS - 1);
    int tile = pi >> 5, l = pi & 31;
    short* Bp = B + (size_t)bb * NPTS * 16 + tile * 512;
    *reinterpret_cast<bf16x8*>(Bp + l * 8)       = b0;   // khalf 0 (lane h=0)
    *reinterpret_cast<bf16x8*>(Bp + 256 + l * 8) = b1;   // khalf 1 (lane h=1)
}

// lane-merge: combine two row-registers across lane-pairs (xor m).
#define MERGE(dst, u, v, m) {                       \
    float _own = (lane & (m)) ? (v) : (u);          \
    float _sel = (lane & (m)) ? (u) : (v);          \
    dst = fminf(_own, __shfl_xor(_sel, (m))); }

// merge one 64-row group (two 16-reg acc sets) -> 1 rowmin per lane, store.
#define EPI(A0, A1, ROWOFF) {                                                  \
    _Pragma("unroll") for (int k = 0; k < 8; ++k) { MERGE(A0[k], A0[2*k], A0[2*k+1], 1); } \
    _Pragma("unroll") for (int k = 0; k < 8; ++k) { MERGE(A1[k], A1[2*k], A1[2*k+1], 1); } \
    _Pragma("unroll") for (int k = 0; k < 4; ++k) { MERGE(A0[k], A0[2*k], A0[2*k+1], 2); } \
    _Pragma("unroll") for (int k = 0; k < 4; ++k) { MERGE(A1[k], A1[2*k], A1[2*k+1], 2); } \
    _Pragma("unroll") for (int k = 0; k < 2; ++k) { MERGE(A0[k], A0[2*k], A0[2*k+1], 4); } \
    _Pragma("unroll") for (int k = 0; k < 2; ++k) { MERGE(A1[k], A1[2*k], A1[2*k+1], 4); } \
    MERGE(A0[0], A0[0], A0[1], 8);                                             \
    MERGE(A1[0], A1[0], A1[1], 8);                                             \
    float fin;                                                                 \
    MERGE(fin, A0[0], A1[0], 16);                                              \
    int row = (lane & 3) + 4 * ((lane >> 5) & 1) + 8 * ((lane >> 2) & 1)       \
            + 16 * ((lane >> 3) & 1) + 32 * ((lane >> 4) & 1);                 \
    rowmin[((size_t)(pass * 2 + colhalf)) * NSET + b * NPTS + row0 + (ROWOFF) + row] = fin; }

// R=4 row-frags per wave (128 rows), direct-global B stream, depth-2
// register prefetch, ZERO barriers / ZERO LDS. Grid 512 = dir x 8b x
// 16 rowgrp(512 rows) x 2 colhalf; 2 blocks/CU, 8 waves/CU.
// Per pair-iter: 2 B loads feed 8 MFMAs (B-traffic/CU ~1MB ~7.8us < MFMA
// floor 14.4us) + 64 min3 folds (6.8us total, hides under MFMA).
__global__ __launch_bounds__(256, 2) void chamfer_mfma_kernel(
    const short* __restrict__ targA, const short* __restrict__ targB,
    const short* __restrict__ predA, const short* __restrict__ predB,
    float* __restrict__ rowmin)   // [2 dir][2 half][NSET]
{
    const int bid  = blockIdx.x;
    const int pass = bid >> 8;
    const int b    = (bid >> 5) & 7;
    const int rowgrp  = (bid >> 1) & 15;
    const int colhalf = bid & 1;
    const int wave = threadIdx.x >> 6;
    const int lane = threadIdx.x & 63;
    const int l31  = lane & 31, h = lane >> 5;

    const short* Af = pass ? predA : targA;
    const short* Bf = pass ? targB : predB;

    const int row0 = rowgrp * 512 + wave * 128;
    const short* abase = Af + ((size_t)(b * NPTS + row0 + l31)) * 16 + h * 8;
    bf16x8 a0 = *reinterpret_cast<const bf16x8*>(abase);              // rows +0..31
    bf16x8 a1 = *reinterpret_cast<const bf16x8*>(abase + 1 * 32 * 16);
    bf16x8 a2 = *reinterpret_cast<const bf16x8*>(abase + 2 * 32 * 16);
    bf16x8 a3 = *reinterpret_cast<const bf16x8*>(abase + 3 * 32 * 16); // +96..127

    const char* bbase = (const char*)Bf + (size_t)b * NPTS * 32
                      + (size_t)colhalf * (NPTS / 2) * 32;   // 128KB frag-ordered

    float acc0[16], acc1[16], acc2[16], acc3[16];
#pragma unroll
    for (int r = 0; r < 16; ++r) {
        acc0[r] = 3.4e38f; acc1[r] = 3.4e38f;
        acc2[r] = 3.4e38f; acc3[r] = 3.4e38f;
    }

    const f32x16 z = {0.f,0.f,0.f,0.f, 0.f,0.f,0.f,0.f, 0.f,0.f,0.f,0.f, 0.f,0.f,0.f,0.f};

#define LDT(t) (*reinterpret_cast<const bf16x8*>(bbase + (size_t)(t) * 1024 + lane * 16))
#define STEP(acc, af) {                                                        \
    f32x16 ca = __builtin_amdgcn_mfma_f32_32x32x16_bf16(af, c0a, z, 0, 0, 0);  \
    f32x16 cb = __builtin_amdgcn_mfma_f32_32x32x16_bf16(af, c0b, z, 0, 0, 0);  \
    _Pragma("unroll") for (int r = 0; r < 16; ++r)                             \
        acc[r] = fminf(fminf(acc[r], ca[r]), cb[r]); /* -> v_min3_f32 */ }

    bf16x8 c0a = LDT(0), c0b = LDT(1);   // current pair
    bf16x8 c1a = LDT(2), c1b = LDT(3);   // next pair

    for (int it = 0; it < 64; ++it) {
        int tp = (it < 62) ? (2 * it + 4) : 124;   // clamped (uniform scalar)
        bf16x8 n0 = LDT(tp);
        bf16x8 n1 = LDT(tp + 1);
        STEP(acc0, a0);
        STEP(acc1, a1);
        STEP(acc2, a2);
        STEP(acc3, a3);
        c0a = c1a; c0b = c1b; c1a = n0; c1b = n1;
    }
#undef STEP
#undef LDT

    EPI(acc0, acc1, 0);    // rows row0 +  0..63
    EPI(acc2, acc3, 64);   // rows row0 + 64..127
}

// min the two col-halves, sum -> one partial per block (no atomics, no init).
__global__ __launch_bounds__(256) void reduce_kernel(const float* __restrict__ rowmin,
                                                     float* __restrict__ partials) {
    const int stride = gridDim.x * 256;
    float v = 0.0f;
    for (int i = blockIdx.x * 256 + threadIdx.x; i < 2 * NSET; i += stride) {
        int d = i >> 16;   // NSET = 65536
        size_t base = (size_t)i + (size_t)d * NSET;
        v += fminf(rowmin[base], rowmin[base + NSET]);
    }
#pragma unroll
    for (int o = 32; o > 0; o >>= 1) v += __shfl_xor(v, o);
    __shared__ float wpart[4];
    if ((threadIdx.x & 63) == 0) wpart[threadIdx.x >> 6] = v;
    __syncthreads();
    if (threadIdx.x == 0)
        partials[blockIdx.x] = wpart[0] + wpart[1] + wpart[2] + wpart[3];
}

__global__ __launch_bounds__(128) void final_kernel(const float* __restrict__ partials,
                                                    float* __restrict__ out) {
    __shared__ float wpart[2];
    float v = partials[threadIdx.x];
#pragma unroll
    for (int o = 32; o > 0; o >>= 1) v += __shfl_xor(v, o);
    if ((threadIdx.x & 63) == 0) wpart[threadIdx.x >> 6] = v;
    __syncthreads();
    if (threadIdx.x == 0)
        out[0] = (wpart[0] + wpart[1]) * (1.0f / (float)NSET);
}

extern "C" void kernel_launch(void* const* d_in, const int* in_sizes, int n_in,
                              void* d_out, int out_size, void* d_ws, size_t ws_size,
                              hipStream_t stream) {
    const float* pred   = (const float*)d_in[0];   // [8,8192,3]
    const float* target = (const float*)d_in[1];   // [8,8192,3]
    float* out = (float*)d_out;

    char* ws = (char*)d_ws;
    float* rowmin   = (float*)ws;                       // 4*NSET floats = 1MB
    float* partials = rowmin + (size_t)4 * NSET;        // 128 floats
    short* tA = (short*)(ws + (size_t)4 * NSET * 4 + 4096);  // each 2 MB
    short* tB = tA + (size_t)NSET * 16;
    short* pA = tB + (size_t)NSET * 16;
    short* pB = pA + (size_t)NSET * 16;

    pack2_kernel<<<2 * NSET / 256, 256, 0, stream>>>(target, pred, tA, tB, pA, pB);

    chamfer_mfma_kernel<<<512, 256, 0, stream>>>(tA, tB, pA, pB, rowmin);

    reduce_kernel<<<128, 256, 0, stream>>>(rowmin, partials);
    final_kernel<<<1, 128, 0, stream>>>(partials, out);
}